// Round 1
// baseline (244.997 us; speedup 1.0000x reference)
//
#include <hip/hip_runtime.h>
#include <cstdint>

// B=16384, D=512, U=512, K=D+U=1024, N=4U=2048
#define NB_B 16384
#define HU 8388608  // 16384*512, offset of c-part in out

typedef __attribute__((ext_vector_type(8))) short short8_t;
typedef __attribute__((ext_vector_type(4))) float float4_t;
typedef __attribute__((ext_vector_type(4))) unsigned int uint4_t;
typedef __attribute__((ext_vector_type(2))) unsigned int uint2_t;

__device__ __forceinline__ unsigned short f2bf(float x) {
    unsigned u = __builtin_bit_cast(unsigned, x);
    u += 0x7fffu + ((u >> 16) & 1u);  // RNE
    return (unsigned short)(u >> 16);
}

__device__ __forceinline__ void gll16(const void* g, const void* lds) {
    // CK-style addrspace detour: flat LDS pointer low 32 bits == LDS offset.
    __builtin_amdgcn_global_load_lds(
        (const __attribute__((address_space(1))) unsigned int*)(uintptr_t)g,
        (__attribute__((address_space(3))) unsigned int*)(unsigned int)(uintptr_t)lds,
        16, 0, 0);
}

__device__ __forceinline__ float sigm(float x) {
    return __builtin_amdgcn_rcpf(1.f + __expf(-x));
}
__device__ __forceinline__ float tanhfast(float x) {
    float ax = fabsf(x);
    float e = __expf(-2.f * ax);               // e in (0,1], no overflow
    float r = (1.f - e) * __builtin_amdgcn_rcpf(1.f + e);
    return copysignf(r, x);
}

// ---------- pre-pass 1: xh[b][k] = bf16(k<512 ? x[b][k] : h[b][k-512]) ----------
__global__ __launch_bounds__(256) void cvt_xh(const float* __restrict__ x,
                                              const float* __restrict__ h,
                                              unsigned short* __restrict__ xh) {
    int n = blockIdx.x * 256 + threadIdx.x;
    int e8 = n * 8;                       // 8 elements per thread
    int row = e8 >> 10, col = e8 & 1023;
    const float* src = (col < 512) ? (x + row * 512 + col) : (h + row * 512 + (col - 512));
    float4_t lo = *(const float4_t*)src;
    float4_t hi = *(const float4_t*)(src + 4);
    uint4_t o;
    o.x = (unsigned)f2bf(lo.x) | ((unsigned)f2bf(lo.y) << 16);
    o.y = (unsigned)f2bf(lo.z) | ((unsigned)f2bf(lo.w) << 16);
    o.z = (unsigned)f2bf(hi.x) | ((unsigned)f2bf(hi.y) << 16);
    o.w = (unsigned)f2bf(hi.z) | ((unsigned)f2bf(hi.w) << 16);
    *(uint4_t*)(xh + e8) = o;
}

// ---------- pre-pass 2: Btw[n'][k] = bf16(Wall[k][n]), n' = ub*128 + uo*4 + g ----------
__global__ __launch_bounds__(256) void xpose_wr(const float* __restrict__ W,
                                                const float* __restrict__ R,
                                                unsigned short* __restrict__ btw) {
    __shared__ float t[32 * 33];
    int gid = blockIdx.x;
    int kt = gid & 31, ub = (gid >> 5) & 15, g = gid >> 9;
    int tid = threadIdx.x;
    // load 32k x 32n fp32 tile, coalesced along n
    int ky = tid >> 3, ux4 = (tid & 7) * 4;
    int kg = kt * 32 + ky;
    int col = g * 512 + ub * 32 + ux4;
    const float* src = (kg < 512) ? (W + (size_t)kg * 2048 + col)
                                  : (R + (size_t)(kg - 512) * 2048 + col);
    float4_t v = *(const float4_t*)src;
    t[ky * 33 + ux4 + 0] = v.x;
    t[ky * 33 + ux4 + 1] = v.y;
    t[ky * 33 + ux4 + 2] = v.z;
    t[ky * 33 + ux4 + 3] = v.w;
    __syncthreads();
    // store transposed, coalesced along k, bf16
    int uo = tid >> 3, kx4 = (tid & 7) * 4;
    unsigned short o0 = f2bf(t[(kx4 + 0) * 33 + uo]);
    unsigned short o1 = f2bf(t[(kx4 + 1) * 33 + uo]);
    unsigned short o2 = f2bf(t[(kx4 + 2) * 33 + uo]);
    unsigned short o3 = f2bf(t[(kx4 + 3) * 33 + uo]);
    uint2_t p;
    p.x = (unsigned)o0 | ((unsigned)o1 << 16);
    p.y = (unsigned)o2 | ((unsigned)o3 << 16);
    *(uint2_t*)(btw + (size_t)(ub * 128 + uo * 4 + g) * 1024 + kt * 32 + kx4) = p;
}

// ---------- main: 128x128 tile GEMM (K=1024) + fused LSTM epilogue ----------
__global__ __launch_bounds__(256, 2) void lstm_main(
    const unsigned short* __restrict__ xh,   // [16384][1024] bf16
    const unsigned short* __restrict__ btw,  // [2048][1024] bf16, gate-interleaved rows
    const float* __restrict__ c_tm1,         // [16384][512]
    const float* __restrict__ pw,            // [512][3]
    const float* __restrict__ bias,          // [2048]
    float* __restrict__ out)                 // [2][16384][512]
{
    __shared__ short As[128 * 32];
    __shared__ short Bs[128 * 32];
    __shared__ float zs[64 * 132];           // half-tile z, row-major, +4 pad
    __shared__ float4_t bias4s[32];
    __shared__ float pwis[32], pwfs[32], pwos[32];

    int tid = threadIdx.x;
    int w = tid >> 6, lane = tid & 63;
    int bid = blockIdx.x;
    int nb = bid & 15, mb = bid >> 4;
    int u0 = nb * 32;

    if (tid < 32) {
        int u = u0 + tid;
        float4_t b4;
        b4.x = bias[u]; b4.y = bias[512 + u]; b4.z = bias[1024 + u]; b4.w = bias[1536 + u];
        bias4s[tid] = b4;
        pwis[tid] = pw[u * 3 + 0];
        pwfs[tid] = pw[u * 3 + 1];
        pwos[tid] = pw[u * 3 + 2];
    }

    float4_t acc[4][4];
#pragma unroll
    for (int i = 0; i < 4; i++)
#pragma unroll
        for (int j = 0; j < 4; j++) acc[i][j] = (float4_t){0.f, 0.f, 0.f, 0.f};

    int m = lane & 15, q = lane >> 4;
    int wrow = w & 1, wcol = w >> 1;

    // staging: each wave stages rows [w*32, w*32+32) of A and B via 2x global_load_lds each
    const unsigned short* aG = xh + (size_t)(mb * 128 + w * 32 + (lane >> 2)) * 1024 + (lane & 3) * 8;
    const unsigned short* bG = btw + (size_t)(nb * 128 + w * 32 + (lane >> 2)) * 1024 + (lane & 3) * 8;
    short* aS0 = &As[(w * 32) * 32];
    short* aS1 = &As[(w * 32 + 16) * 32];
    short* bS0 = &Bs[(w * 32) * 32];
    short* bS1 = &Bs[(w * 32 + 16) * 32];

    for (int kt = 0; kt < 32; ++kt) {
        int ko = kt * 32;
        gll16(aG + ko, aS0);
        gll16(aG + ko + 16 * 1024, aS1);
        gll16(bG + ko, bS0);
        gll16(bG + ko + 16 * 1024, bS1);
        __syncthreads();
        short8_t a[4], b[4];
#pragma unroll
        for (int i = 0; i < 4; i++)
            a[i] = *(const short8_t*)&As[(wrow * 64 + i * 16 + m) * 32 + q * 8];
#pragma unroll
        for (int j = 0; j < 4; j++)
            b[j] = *(const short8_t*)&Bs[(wcol * 64 + j * 16 + m) * 32 + q * 8];
#pragma unroll
        for (int i = 0; i < 4; i++)
#pragma unroll
            for (int j = 0; j < 4; j++)
                acc[i][j] = __builtin_amdgcn_mfma_f32_16x16x32_bf16(a[i], b[j], acc[i][j], 0, 0, 0);
        __syncthreads();
    }

    // ---- fused epilogue, two 64-row halves ----
#pragma unroll
    for (int hh = 0; hh < 2; ++hh) {
        if (wrow == hh) {
#pragma unroll
            for (int i = 0; i < 4; i++)
#pragma unroll
                for (int j = 0; j < 4; j++) {
                    int c = wcol * 64 + j * 16 + m;
                    int rbase = i * 16 + q * 4;
#pragma unroll
                    for (int r = 0; r < 4; r++)
                        zs[(rbase + r) * 132 + c] = acc[i][j][r];
                }
        }
        __syncthreads();
#pragma unroll
        for (int it = 0; it < 2; ++it) {
            int r = (tid >> 3) + it * 32;            // row within half [0,64)
            int uo4 = (tid & 7) * 4;                 // 4 consecutive u per thread
            int grow = mb * 128 + hh * 64 + r;       // global batch row
            float4_t c14 = *(const float4_t*)&c_tm1[(size_t)grow * 512 + u0 + uo4];
            float4_t pwi4 = *(const float4_t*)&pwis[uo4];
            float4_t pwf4 = *(const float4_t*)&pwfs[uo4];
            float4_t pwo4 = *(const float4_t*)&pwos[uo4];
            float4_t hv, cv;
#pragma unroll
            for (int u = 0; u < 4; ++u) {
                float4_t z4 = *(const float4_t*)&zs[r * 132 + (uo4 + u) * 4];  // (i,f,g,o)
                float4_t b4 = bias4s[uo4 + u];
                float c1 = c14[u];
                float iv = sigm(z4.x + b4.x + c1 * pwi4[u]);
                float fv = sigm(z4.y + b4.y + c1 * pwf4[u]);
                float gv = tanhfast(z4.z + b4.z);
                float cc = fv * c1 + iv * gv;
                float ov = sigm(z4.w + b4.w + cc * pwo4[u]);
                hv[u] = ov * tanhfast(cc);
                cv[u] = cc;
            }
            *(float4_t*)&out[(size_t)grow * 512 + u0 + uo4] = hv;
            *(float4_t*)&out[HU + (size_t)grow * 512 + u0 + uo4] = cv;
        }
        __syncthreads();
    }
}

extern "C" void kernel_launch(void* const* d_in, const int* in_sizes, int n_in,
                              void* d_out, int out_size, void* d_ws, size_t ws_size,
                              hipStream_t stream) {
    const float* x    = (const float*)d_in[0];
    const float* h    = (const float*)d_in[1];
    const float* c    = (const float*)d_in[2];
    const float* W    = (const float*)d_in[3];
    const float* R    = (const float*)d_in[4];
    const float* pw   = (const float*)d_in[5];
    const float* bias = (const float*)d_in[6];
    float* out = (float*)d_out;

    unsigned short* xh  = (unsigned short*)d_ws;                        // 33,554,432 B
    unsigned short* btw = (unsigned short*)((char*)d_ws + 33554432u);   // + 4,194,304 B

    cvt_xh<<<8192, 256, 0, stream>>>(x, h, xh);
    xpose_wr<<<2048, 256, 0, stream>>>(W, R, btw);
    lstm_main<<<2048, 256, 0, stream>>>(xh, btw, c, pw, bias, out);
}